// Round 1
// baseline (55.169 us; speedup 1.0000x reference)
//
#include <hip/hip_runtime.h>

// DeformationPerturbationLayer: the reference's dense [B,N,N] tent-weight
// einsum is exactly bilinear interpolation (tent weights have <=2 nonzero
// taps per axis). Displacement field is analytic (localized bulge):
//   dxc = -(x - 31.5), dyc = -(y - 31.5), g = exp(-(dxc^2+dyc^2)/512)
//   src_x = x + w[b]*dxc*g, src_y = y + w[b]*dyc*g
// out[b,c,y,x] = bilinear(image[c], src_y, src_x) with zero padding.

#define H 64
#define W 64
#define C 3
#define B 8
#define N (H * W)

__global__ __launch_bounds__(256) void deform_bilinear_kernel(
    const float* __restrict__ w,      // [B]
    const float* __restrict__ img,    // [C, H, W]
    float* __restrict__ out)          // [B, C, H, W]
{
    int tid = blockIdx.x * blockDim.x + threadIdx.x;  // 0 .. B*N-1
    int b = tid >> 12;        // / N
    int n = tid & (N - 1);
    int y = n >> 6;
    int x = n & (W - 1);

    const float cx = (W - 1) * 0.5f;   // 31.5
    const float cy = (H - 1) * 0.5f;
    float dxc = -((float)x - cx);
    float dyc = -((float)y - cy);
    float sigma = (float)(H < W ? H : W) * 0.25f;      // 16
    float inv2s2 = 1.0f / (2.0f * sigma * sigma);       // 1/512
    float g = expf(-(dxc * dxc + dyc * dyc) * inv2s2);

    float wb = w[b];
    float sx = (float)x + wb * dxc * g;
    float sy = (float)y + wb * dyc * g;

    float fx0 = floorf(sx);
    float fy0 = floorf(sy);
    int x0 = (int)fx0;
    int y0 = (int)fy0;
    float ax = sx - fx0;
    float ay = sy - fy0;

    // per-tap weights, zeroed when tap is out of bounds
    float wx0 = (x0 >= 0 && x0 < W) ? (1.0f - ax) : 0.0f;
    float wx1 = (x0 + 1 >= 0 && x0 + 1 < W) ? ax : 0.0f;
    float wy0 = (y0 >= 0 && y0 < H) ? (1.0f - ay) : 0.0f;
    float wy1 = (y0 + 1 >= 0 && y0 + 1 < H) ? ay : 0.0f;

    // clamped indices so loads are always in-bounds (weight is 0 if clamped)
    int x0c = min(max(x0, 0), W - 1);
    int x1c = min(max(x0 + 1, 0), W - 1);
    int y0c = min(max(y0, 0), H - 1);
    int y1c = min(max(y0 + 1, 0), H - 1);

    int i00 = (y0c << 6) + x0c;
    int i01 = (y0c << 6) + x1c;
    int i10 = (y1c << 6) + x0c;
    int i11 = (y1c << 6) + x1c;

    float w00 = wy0 * wx0;
    float w01 = wy0 * wx1;
    float w10 = wy1 * wx0;
    float w11 = wy1 * wx1;

#pragma unroll
    for (int c = 0; c < C; ++c) {
        const float* ic = img + (c << 12);
        float v = w00 * ic[i00] + w01 * ic[i01] + w10 * ic[i10] + w11 * ic[i11];
        out[((b * C + c) << 12) + n] = v;
    }
}

extern "C" void kernel_launch(void* const* d_in, const int* in_sizes, int n_in,
                              void* d_out, int out_size, void* d_ws, size_t ws_size,
                              hipStream_t stream) {
    const float* w   = (const float*)d_in[0];   // [8,1]
    const float* img = (const float*)d_in[1];   // [3,64,64]
    float* out = (float*)d_out;                 // [8,3,64,64]

    int total = B * N;  // one thread per (b, y, x)
    int block = 256;
    int grid = (total + block - 1) / block;     // 128
    deform_bilinear_kernel<<<grid, block, 0, stream>>>(w, img, out);
}